// Round 1
// baseline (219.368 us; speedup 1.0000x reference)
//
#include <hip/hip_runtime.h>
#include <hip/hip_bf16.h>

#define B_ 2
#define T_ 2048
#define C_ 1024
#define H_ 16
#define KV_ 4
#define D_ 64
#define M_ (B_*T_)   // 4096

typedef __attribute__((ext_vector_type(4))) float f32x4;
typedef __attribute__((ext_vector_type(8))) short bf16x8;

__device__ __forceinline__ short f2bf(float f) {
  unsigned u = __builtin_bit_cast(unsigned, f);
  u += 0x7FFFu + ((u >> 16) & 1u);   // round-to-nearest-even
  return (short)(u >> 16);
}

__device__ __forceinline__ void gld_lds16(const void* g, void* l) {
  __builtin_amdgcn_global_load_lds(
      (const __attribute__((address_space(1))) void*)g,
      (__attribute__((address_space(3))) void*)l, 16, 0, 0);
}

__device__ __forceinline__ float redmax16(float v) {
  v = fmaxf(v, __shfl_xor(v, 1));
  v = fmaxf(v, __shfl_xor(v, 2));
  v = fmaxf(v, __shfl_xor(v, 4));
  v = fmaxf(v, __shfl_xor(v, 8));
  return v;
}
__device__ __forceinline__ float redsum16(float v) {
  v += __shfl_xor(v, 1);
  v += __shfl_xor(v, 2);
  v += __shfl_xor(v, 4);
  v += __shfl_xor(v, 8);
  return v;
}

// ---------------- cast f32 -> bf16, 4 elems/thread ----------------
__global__ __launch_bounds__(256) void k_cast(const float* __restrict__ in,
                                              short* __restrict__ out, int n) {
  int i = (blockIdx.x * 256 + threadIdx.x) * 4;
  if (i + 3 < n) {
    float4 f = *(const float4*)(in + i);
    short4 s;
    s.x = f2bf(f.x); s.y = f2bf(f.y); s.z = f2bf(f.z); s.w = f2bf(f.w);
    *(short4*)(out + i) = s;
  }
}

// ---------------- transpose + cast: out[c][r] = bf16(in[r][c]) ----------------
// in: R x Ncol f32 row-major; out: Ncol x R bf16 row-major. block (32,8)
__global__ __launch_bounds__(256) void k_transpose_cast(const float* __restrict__ in,
                                                        short* __restrict__ out,
                                                        int R, int Ncol) {
  __shared__ float tile[32][33];
  int c0 = blockIdx.x * 32, r0 = blockIdx.y * 32;
  int tx = threadIdx.x, ty = threadIdx.y;
#pragma unroll
  for (int i = 0; i < 32; i += 8)
    tile[ty + i][tx] = in[(size_t)(r0 + ty + i) * Ncol + c0 + tx];
  __syncthreads();
#pragma unroll
  for (int i = 0; i < 32; i += 8)
    out[(size_t)(c0 + ty + i) * R + r0 + tx] = f2bf(tile[tx][ty + i]);
}

// ---------------- bf16 GEMM: C(MxN f32) = A(MxK) * Bt(NxK)^T ----------------
// 128x128 tile, BK=32, 4 waves (2x2 of 64x64), mfma_f32_16x16x32_bf16
__global__ __launch_bounds__(256) void k_gemm(const short* __restrict__ A,
                                              const short* __restrict__ Bt,
                                              float* __restrict__ C,
                                              int M, int N, int K) {
  __shared__ short sA[128 * 32];
  __shared__ short sB[128 * 32];
  const int tid = threadIdx.x;
  const int wid = tid >> 6, lane = tid & 63;
  const int g = lane >> 4, c = lane & 15;
  const int wm = wid >> 1, wn = wid & 1;
  const int m0 = blockIdx.y * 128, n0 = blockIdx.x * 128;
  const int srow = lane >> 2, scol = (lane & 3) * 8;

  const short* Ag = A + (size_t)(m0 + wid * 32 + srow) * K + scol;
  const short* Bg = Bt + (size_t)(n0 + wid * 32 + srow) * K + scol;
  short* sAd0 = &sA[(wid * 2) * 512];
  short* sAd1 = &sA[(wid * 2 + 1) * 512];
  short* sBd0 = &sB[(wid * 2) * 512];
  short* sBd1 = &sB[(wid * 2 + 1) * 512];

  f32x4 acc[4][4] = {};

  for (int k0 = 0; k0 < K; k0 += 32) {
    gld_lds16(Ag + k0, sAd0);
    gld_lds16(Ag + (size_t)16 * K + k0, sAd1);
    gld_lds16(Bg + k0, sBd0);
    gld_lds16(Bg + (size_t)16 * K + k0, sBd1);
    __syncthreads();
    bf16x8 af[4], bfr[4];
#pragma unroll
    for (int i = 0; i < 4; ++i)
      af[i] = *(const bf16x8*)&sA[(wm * 64 + i * 16 + c) * 32 + g * 8];
#pragma unroll
    for (int j = 0; j < 4; ++j)
      bfr[j] = *(const bf16x8*)&sB[(wn * 64 + j * 16 + c) * 32 + g * 8];
#pragma unroll
    for (int i = 0; i < 4; ++i)
#pragma unroll
      for (int j = 0; j < 4; ++j)
        acc[i][j] = __builtin_amdgcn_mfma_f32_16x16x32_bf16(af[i], bfr[j], acc[i][j], 0, 0, 0);
    __syncthreads();
  }
#pragma unroll
  for (int i = 0; i < 4; ++i)
#pragma unroll
    for (int j = 0; j < 4; ++j) {
      int row = m0 + wm * 64 + i * 16 + g * 4;
      int col = n0 + wn * 64 + j * 16 + c;
      float* cp = C + (size_t)row * N + col;
#pragma unroll
      for (int r = 0; r < 4; ++r) cp[(size_t)r * N] = acc[i][j][r];
    }
}

// ---------------- gate + ve, RoPE, RMS-norm; emit q/k/vT bf16 ----------------
// qkv: (B*T) x 1536 f32 rows = [q 1024 | k 256 | v 256]
// qb: (B,H,T,D)  kb: (B,KV,T,D)  vT: (B,KV,D,T)
__global__ __launch_bounds__(256) void k_post(const float* __restrict__ qkv,
                                              const float* __restrict__ x,
                                              const float* __restrict__ ve,
                                              const float* __restrict__ cosp,
                                              const float* __restrict__ sinp,
                                              const float* __restrict__ Wg,
                                              short* __restrict__ qb,
                                              short* __restrict__ kb,
                                              short* __restrict__ vT) {
  const int row = blockIdx.x;            // b*T + t
  const int b = row >> 11, t = row & (T_ - 1);
  const int wid = threadIdx.x >> 6, lane = threadIdx.x & 63;
  const float* qrow = qkv + (size_t)row * 1536;
  const float cv = cosp[t * 32 + (lane & 31)];
  const float sv = sinp[t * 32 + (lane & 31)];

  for (int vi = wid; vi < 24; vi += 4) {
    if (vi < 20) {
      float val = (vi < 16) ? qrow[vi * 64 + lane] : qrow[1024 + (vi - 16) * 64 + lane];
      float other = __shfl_xor(val, 32);
      // lane<32: x1*cos + x2*sin ; lane>=32: -x1*sin + x2*cos
      float r = (lane < 32) ? fmaf(val, cv, other * sv) : fmaf(val, cv, -other * sv);
      float ss = r * r;
      ss += __shfl_xor(ss, 1);  ss += __shfl_xor(ss, 2);  ss += __shfl_xor(ss, 4);
      ss += __shfl_xor(ss, 8);  ss += __shfl_xor(ss, 16); ss += __shfl_xor(ss, 32);
      float outv = r * rsqrtf(ss * (1.0f / 64.0f) + 1.1920929e-07f);
      if (vi < 16)
        qb[((size_t)(b * H_ + vi) * T_ + t) * D_ + lane] = f2bf(outv);
      else
        kb[((size_t)(b * KV_ + (vi - 16)) * T_ + t) * D_ + lane] = f2bf(outv);
    } else {
      int kvh = vi - 20;
      float val = qrow[1280 + kvh * 64 + lane];
      float xg = (lane < 32) ? x[(size_t)row * C_ + lane] * Wg[lane * KV_ + kvh] : 0.0f;
      xg += __shfl_xor(xg, 1);  xg += __shfl_xor(xg, 2);  xg += __shfl_xor(xg, 4);
      xg += __shfl_xor(xg, 8);  xg += __shfl_xor(xg, 16); xg += __shfl_xor(xg, 32);
      float gate = 2.0f / (1.0f + __expf(-xg));
      float vvv = fmaf(gate, ve[(size_t)row * (KV_ * D_) + kvh * 64 + lane], val);
      vT[((size_t)(b * KV_ + kvh) * D_ + lane) * T_ + t] = f2bf(vvv);
    }
  }
}

// ---------------- flash attention, sliding window causal ----------------
// 4 independent waves per block; wave = 16 q rows. K/V direct from global (L2).
__global__ __launch_bounds__(256) void k_attn(const short* __restrict__ qg,
                                              const short* __restrict__ kg,
                                              const short* __restrict__ vg,
                                              short* __restrict__ yb,
                                              const int* __restrict__ winp) {
  const int wsz = *winp;
  const int qt = blockIdx.x, bh = blockIdx.y;
  const int b = bh >> 4, h = bh & 15;
  const int kvh = h >> 2;                    // GQA: kv = h // 4
  const int wid = threadIdx.x >> 6, lane = threadIdx.x & 63;
  const int g = lane >> 4, c = lane & 15;
  const int t0 = qt * 64 + wid * 16;
  __shared__ short spt[4][16][72];           // per-wave P tile, padded rows (144B)

  const short* qbase = qg + ((size_t)(b * H_ + h) * T_ + t0) * D_;
  const bf16x8 aq0 = *(const bf16x8*)(qbase + c * D_ + g * 8);
  const bf16x8 aq1 = *(const bf16x8*)(qbase + c * D_ + 32 + g * 8);
  const short* kbase = kg + (size_t)(b * KV_ + kvh) * T_ * D_;
  const short* vbase = vg + (size_t)(b * KV_ + kvh) * D_ * T_;

  float m[4], l[4];
  f32x4 o[4] = {};
#pragma unroll
  for (int r = 0; r < 4; ++r) { m[r] = -1e30f; l[r] = 0.0f; }

  int lo = t0 - wsz + 1; if (lo < 0) lo = 0;
  const int kt_lo = lo >> 6, kt_hi = (t0 + 15) >> 6;

  for (int kt = kt_lo; kt <= kt_hi; ++kt) {
    const int kc0 = kt * 64;
    f32x4 s[4] = {};
#pragma unroll
    for (int cj = 0; cj < 4; ++cj) {
      const short* kr = kbase + (size_t)(kc0 + cj * 16 + c) * D_ + g * 8;
      bf16x8 bk0 = *(const bf16x8*)kr;
      bf16x8 bk1 = *(const bf16x8*)(kr + 32);
      s[cj] = __builtin_amdgcn_mfma_f32_16x16x32_bf16(aq0, bk0, s[cj], 0, 0, 0);
      s[cj] = __builtin_amdgcn_mfma_f32_16x16x32_bf16(aq1, bk1, s[cj], 0, 0, 0);
    }
    float p[4][4], tmax[4];
#pragma unroll
    for (int r = 0; r < 4; ++r) tmax[r] = -1e30f;
#pragma unroll
    for (int cj = 0; cj < 4; ++cj) {
      const int col = kc0 + cj * 16 + c;
#pragma unroll
      for (int r = 0; r < 4; ++r) {
        const int rowg = t0 + g * 4 + r;
        float svv = s[cj][r] * 0.125f;
        svv = (col <= rowg && col > rowg - wsz) ? svv : -1e30f;
        p[cj][r] = svv;
        tmax[r] = fmaxf(tmax[r], svv);
      }
    }
    float fr[4];
#pragma unroll
    for (int r = 0; r < 4; ++r) {
      float tm = redmax16(tmax[r]);
      float nm = fmaxf(m[r], tm);
      fr[r] = __expf(m[r] - nm);
      m[r] = nm;
    }
    float psum[4] = {0.f, 0.f, 0.f, 0.f};
#pragma unroll
    for (int cj = 0; cj < 4; ++cj)
#pragma unroll
      for (int r = 0; r < 4; ++r) {
        float pv = __expf(p[cj][r] - m[r]);
        p[cj][r] = pv;
        psum[r] += pv;
      }
#pragma unroll
    for (int r = 0; r < 4; ++r) l[r] = l[r] * fr[r] + redsum16(psum[r]);
#pragma unroll
    for (int nd = 0; nd < 4; ++nd)
#pragma unroll
      for (int r = 0; r < 4; ++r) o[nd][r] *= fr[r];
    // P (C-layout) -> LDS -> A-layout frags
#pragma unroll
    for (int cj = 0; cj < 4; ++cj)
#pragma unroll
      for (int r = 0; r < 4; ++r)
        spt[wid][g * 4 + r][cj * 16 + c] = f2bf(p[cj][r]);
    asm volatile("s_waitcnt lgkmcnt(0)" ::: "memory");
#pragma unroll
    for (int ks = 0; ks < 2; ++ks) {
      bf16x8 ap = *(const bf16x8*)&spt[wid][c][ks * 32 + g * 8];
#pragma unroll
      for (int nd = 0; nd < 4; ++nd) {
        const short* vr = vbase + (size_t)(nd * 16 + c) * T_ + kc0 + ks * 32 + g * 8;
        bf16x8 bv = *(const bf16x8*)vr;
        o[nd] = __builtin_amdgcn_mfma_f32_16x16x32_bf16(ap, bv, o[nd], 0, 0, 0);
      }
    }
  }
#pragma unroll
  for (int nd = 0; nd < 4; ++nd)
#pragma unroll
    for (int r = 0; r < 4; ++r) {
      const int rowg = t0 + g * 4 + r;
      float ov = o[nd][r] / l[r];
      yb[((size_t)b * T_ + rowg) * C_ + h * D_ + nd * 16 + c] = f2bf(ov);
    }
}

extern "C" void kernel_launch(void* const* d_in, const int* in_sizes, int n_in,
                              void* d_out, int out_size, void* d_ws, size_t ws_size,
                              hipStream_t stream) {
  const float* x    = (const float*)d_in[0];
  const float* ve   = (const float*)d_in[1];
  const float* cosp = (const float*)d_in[2];
  const float* sinp = (const float*)d_in[3];
  const float* Wq   = (const float*)d_in[4];
  const float* Wk   = (const float*)d_in[5];
  const float* Wv   = (const float*)d_in[6];
  const float* Wo   = (const float*)d_in[7];
  const float* Wg   = (const float*)d_in[8];
  const int*   winp = (const int*)d_in[9];
  float* out = (float*)d_out;
  char* ws = (char*)d_ws;

  const size_t MB = 1024 * 1024;
  short* xb   = (short*)(ws);              // 8 MiB : x bf16 (4096x1024)
  short* wT   = (short*)(ws + 8  * MB);    // 3 MiB : [Wq|Wk|Wv]^T bf16 (1536x1024)
  short* woT  = (short*)(ws + 11 * MB);    // 2 MiB : Wo^T bf16 (1024x1024)
  float* qkv  = (float*)(ws + 13 * MB);    // 24 MiB: qkv f32 (4096x1536)
  short* qb   = (short*)(ws + 37 * MB);    // 8 MiB : q bf16 (B,H,T,D)
  short* kbuf = (short*)(ws + 45 * MB);    // 2 MiB : k bf16 (B,KV,T,D)
  short* vT   = (short*)(ws + 47 * MB);    // 2 MiB : v bf16 (B,KV,D,T)
  short* yb   = (short*)(ws + 49 * MB);    // 8 MiB : attn out bf16 (B,T,C)

  dim3 tb(32, 8);
  k_cast<<<4096, 256, 0, stream>>>(x, xb, M_ * C_);
  k_transpose_cast<<<dim3(32, 32), tb, 0, stream>>>(Wq, wT, 1024, 1024);
  k_transpose_cast<<<dim3(8, 32),  tb, 0, stream>>>(Wk, wT + (size_t)1024 * 1024, 1024, 256);
  k_transpose_cast<<<dim3(8, 32),  tb, 0, stream>>>(Wv, wT + (size_t)1280 * 1024, 1024, 256);
  k_transpose_cast<<<dim3(32, 32), tb, 0, stream>>>(Wo, woT, 1024, 1024);

  k_gemm<<<dim3(12, 32), 256, 0, stream>>>(xb, wT, qkv, M_, 1536, 1024);
  k_post<<<4096, 256, 0, stream>>>(qkv, x, ve, cosp, sinp, Wg, qb, kbuf, vT);
  k_attn<<<dim3(32, 32), 256, 0, stream>>>(qb, kbuf, vT, yb, winp);
  k_gemm<<<dim3(8, 32), 256, 0, stream>>>(yb, woT, out, M_, 1024, 1024);
}

// Round 4
// 216.486 us; speedup vs baseline: 1.0133x; 1.0133x over previous
//
#include <hip/hip_runtime.h>
#include <hip/hip_bf16.h>

#define B_ 2
#define T_ 2048
#define C_ 1024
#define H_ 16
#define KV_ 4
#define D_ 64
#define M_ (B_*T_)   // 4096

typedef __attribute__((ext_vector_type(4))) float f32x4;
typedef __attribute__((ext_vector_type(8))) short bf16x8;

__device__ __forceinline__ float exp2fast(float x) {
  return __builtin_amdgcn_exp2f(x);   // v_exp_f32 (2^x)
}

__device__ __forceinline__ unsigned short f2bfu(float f) {
  unsigned u = __builtin_bit_cast(unsigned, f);
  u += 0x7FFFu + ((u >> 16) & 1u);   // round-to-nearest-even
  return (unsigned short)(u >> 16);
}

__device__ __forceinline__ short f2bf(float f) {
  return (short)f2bfu(f);
}

__device__ __forceinline__ unsigned pack2bf(float a, float b) {
  return (unsigned)f2bfu(a) | ((unsigned)f2bfu(b) << 16);
}

__device__ __forceinline__ void gld_lds16(const void* g, void* l) {
  __builtin_amdgcn_global_load_lds(
      (const __attribute__((address_space(1))) void*)g,
      (__attribute__((address_space(3))) void*)l, 16, 0, 0);
}

// ---------------- cast f32 -> bf16, 4 elems/thread ----------------
__global__ __launch_bounds__(256) void k_cast(const float* __restrict__ in,
                                              short* __restrict__ out, int n) {
  int i = (blockIdx.x * 256 + threadIdx.x) * 4;
  if (i + 3 < n) {
    float4 f = *(const float4*)(in + i);
    short4 s;
    s.x = f2bf(f.x); s.y = f2bf(f.y); s.z = f2bf(f.z); s.w = f2bf(f.w);
    *(short4*)(out + i) = s;
  }
}

// ---------------- fused transpose+cast of Wq|Wk|Wv and Wo ----------------
// grid (80, 32), block (32,8). out[c][r] = bf16(in[r][c]); R = 1024 for all.
__global__ __launch_bounds__(256) void k_transpose_all(const float* __restrict__ Wq,
                                                       const float* __restrict__ Wk,
                                                       const float* __restrict__ Wv,
                                                       const float* __restrict__ Wo,
                                                       short* __restrict__ wT,
                                                       short* __restrict__ woT) {
  __shared__ float tile[32][33];
  int bx = blockIdx.x;
  const float* in; short* out; int Ncol, cb;
  if (bx < 32)      { in = Wq; out = wT;                       Ncol = 1024; cb = bx; }
  else if (bx < 40) { in = Wk; out = wT + (size_t)1024 * 1024; Ncol = 256;  cb = bx - 32; }
  else if (bx < 48) { in = Wv; out = wT + (size_t)1280 * 1024; Ncol = 256;  cb = bx - 40; }
  else              { in = Wo; out = woT;                      Ncol = 1024; cb = bx - 48; }
  const int R = 1024;
  int c0 = cb * 32, r0 = blockIdx.y * 32;
  int tx = threadIdx.x, ty = threadIdx.y;
#pragma unroll
  for (int i = 0; i < 32; i += 8)
    tile[ty + i][tx] = in[(size_t)(r0 + ty + i) * Ncol + c0 + tx];
  __syncthreads();
#pragma unroll
  for (int i = 0; i < 32; i += 8)
    out[(size_t)(c0 + ty + i) * R + r0 + tx] = f2bf(tile[tx][ty + i]);
}

// ---------------- bf16 GEMM: C(MxN f32) = A(MxK) * Bt(NxK)^T ----------------
// 128x128 tile, BK=32, 4 waves (2x2 of 64x64), mfma_f32_16x16x32_bf16
__global__ __launch_bounds__(256) void k_gemm(const short* __restrict__ A,
                                              const short* __restrict__ Bt,
                                              float* __restrict__ C,
                                              int M, int N, int K) {
  __shared__ short sA[128 * 32];
  __shared__ short sB[128 * 32];
  const int tid = threadIdx.x;
  const int wid = tid >> 6, lane = tid & 63;
  const int g = lane >> 4, c = lane & 15;
  const int wm = wid >> 1, wn = wid & 1;
  const int m0 = blockIdx.y * 128, n0 = blockIdx.x * 128;
  const int srow = lane >> 2, scol = (lane & 3) * 8;

  const short* Ag = A + (size_t)(m0 + wid * 32 + srow) * K + scol;
  const short* Bg = Bt + (size_t)(n0 + wid * 32 + srow) * K + scol;
  short* sAd0 = &sA[(wid * 2) * 512];
  short* sAd1 = &sA[(wid * 2 + 1) * 512];
  short* sBd0 = &sB[(wid * 2) * 512];
  short* sBd1 = &sB[(wid * 2 + 1) * 512];

  f32x4 acc[4][4] = {};

  for (int k0 = 0; k0 < K; k0 += 32) {
    gld_lds16(Ag + k0, sAd0);
    gld_lds16(Ag + (size_t)16 * K + k0, sAd1);
    gld_lds16(Bg + k0, sBd0);
    gld_lds16(Bg + (size_t)16 * K + k0, sBd1);
    __syncthreads();
    bf16x8 af[4], bfr[4];
#pragma unroll
    for (int i = 0; i < 4; ++i)
      af[i] = *(const bf16x8*)&sA[(wm * 64 + i * 16 + c) * 32 + g * 8];
#pragma unroll
    for (int j = 0; j < 4; ++j)
      bfr[j] = *(const bf16x8*)&sB[(wn * 64 + j * 16 + c) * 32 + g * 8];
#pragma unroll
    for (int i = 0; i < 4; ++i)
#pragma unroll
      for (int j = 0; j < 4; ++j)
        acc[i][j] = __builtin_amdgcn_mfma_f32_16x16x32_bf16(af[i], bfr[j], acc[i][j], 0, 0, 0);
    __syncthreads();
  }
#pragma unroll
  for (int i = 0; i < 4; ++i)
#pragma unroll
    for (int j = 0; j < 4; ++j) {
      int row = m0 + wm * 64 + i * 16 + g * 4;
      int col = n0 + wn * 64 + j * 16 + c;
      float* cp = C + (size_t)row * N + col;
#pragma unroll
      for (int r = 0; r < 4; ++r) cp[(size_t)r * N] = acc[i][j][r];
    }
}

// ---------------- gate + ve, RoPE, RMS-norm; emit q/k/vT bf16 ----------------
// qkv: (B*T) x 1536 f32 rows = [q 1024 | k 256 | v 256]
// qb: (B,H,T,D)  kb: (B,KV,T,D)  vT: (B,KV,D,T)
__global__ __launch_bounds__(256) void k_post(const float* __restrict__ qkv,
                                              const float* __restrict__ x,
                                              const float* __restrict__ ve,
                                              const float* __restrict__ cosp,
                                              const float* __restrict__ sinp,
                                              const float* __restrict__ Wg,
                                              short* __restrict__ qb,
                                              short* __restrict__ kb,
                                              short* __restrict__ vT) {
  const int row = blockIdx.x;            // b*T + t
  const int b = row >> 11, t = row & (T_ - 1);
  const int wid = threadIdx.x >> 6, lane = threadIdx.x & 63;
  const float* qrow = qkv + (size_t)row * 1536;
  const float cv = cosp[t * 32 + (lane & 31)];
  const float sv = sinp[t * 32 + (lane & 31)];

  for (int vi = wid; vi < 24; vi += 4) {
    if (vi < 20) {
      float val = (vi < 16) ? qrow[vi * 64 + lane] : qrow[1024 + (vi - 16) * 64 + lane];
      float other = __shfl_xor(val, 32);
      float r = (lane < 32) ? fmaf(val, cv, other * sv) : fmaf(val, cv, -other * sv);
      float ss = r * r;
      ss += __shfl_xor(ss, 1);  ss += __shfl_xor(ss, 2);  ss += __shfl_xor(ss, 4);
      ss += __shfl_xor(ss, 8);  ss += __shfl_xor(ss, 16); ss += __shfl_xor(ss, 32);
      float outv = r * rsqrtf(ss * (1.0f / 64.0f) + 1.1920929e-07f);
      if (vi < 16)
        qb[((size_t)(b * H_ + vi) * T_ + t) * D_ + lane] = f2bf(outv);
      else
        kb[((size_t)(b * KV_ + (vi - 16)) * T_ + t) * D_ + lane] = f2bf(outv);
    } else {
      int kvh = vi - 20;
      float val = qrow[1280 + kvh * 64 + lane];
      float xg = (lane < 32) ? x[(size_t)row * C_ + lane] * Wg[lane * KV_ + kvh] : 0.0f;
      xg += __shfl_xor(xg, 1);  xg += __shfl_xor(xg, 2);  xg += __shfl_xor(xg, 4);
      xg += __shfl_xor(xg, 8);  xg += __shfl_xor(xg, 16); xg += __shfl_xor(xg, 32);
      float gate = 2.0f / (1.0f + __expf(-xg));
      float vvv = fmaf(gate, ve[(size_t)row * (KV_ * D_) + kvh * 64 + lane], val);
      vT[((size_t)(b * KV_ + kvh) * D_ + lane) * T_ + t] = f2bf(vvv);
    }
  }
}

// ---------------- flash attention, swapped-operand, sliding window ----------------
// 4 independent waves / block, wave = 16 q rows. S^T = mfma(K,Q): lane owns
// q = lane&15 -> scalar m,l. O^T = mfma(V,P): output col = q too. K/V from
// global (L2-resident); K prefetched one tile ahead into the same regs.
__global__ __launch_bounds__(256, 4) void k_attn(const short* __restrict__ qg,
                                                 const short* __restrict__ kg,
                                                 const short* __restrict__ vg,
                                                 short* __restrict__ yb,
                                                 const int* __restrict__ winp) {
  const int wsz = *winp;
  const int qt = blockIdx.x, bh = blockIdx.y;
  const int b = bh >> 4, h = bh & 15;
  const int kvh = h >> 2;
  const int wid = threadIdx.x >> 6, lane = threadIdx.x & 63;
  const int g = lane >> 4, c = lane & 15;
  const int t0 = qt * 64 + wid * 16;
  __shared__ short spt_all[4][16][72];
  short (*spt)[72] = spt_all[wid];

  const short* qbase = qg + ((size_t)(b * H_ + h) * T_ + t0) * D_;
  const bf16x8 bq0 = *(const bf16x8*)(qbase + c * D_ + g * 8);
  const bf16x8 bq1 = *(const bf16x8*)(qbase + c * D_ + 32 + g * 8);
  const short* kbase = kg + (size_t)(b * KV_ + kvh) * T_ * D_;
  const short* vbase = vg + (size_t)(b * KV_ + kvh) * D_ * T_;

  float m = -20000.0f, l = 0.0f;
  f32x4 o[4] = {};

  int lo = t0 - wsz + 1; if (lo < 0) lo = 0;
  const int kt_lo = lo >> 6, kt_hi = (t0 + 15) >> 6;
  const int qgl = t0 + c;
  const float SC2 = 0.125f * 1.44269504088896340736f;   // scale * log2(e)

  // preload K tile kt_lo (A-operand frags: row = kv within 16-block, k = d)
  bf16x8 bk[8];
  {
    const short* kr0 = kbase + (size_t)(kt_lo * 64 + c) * D_ + g * 8;
#pragma unroll
    for (int cj = 0; cj < 4; ++cj) {
      bk[2 * cj]     = *(const bf16x8*)(kr0 + cj * 16 * D_);
      bk[2 * cj + 1] = *(const bf16x8*)(kr0 + cj * 16 * D_ + 32);
    }
  }

  for (int kt = kt_lo; kt <= kt_hi; ++kt) {
    const int kc0 = kt * 64;
    // V tile loads issued early (consumed after softmax)
    bf16x8 bv[8];
    {
      const short* vr0 = vbase + (size_t)c * T_ + kc0 + g * 8;
#pragma unroll
      for (int nd = 0; nd < 4; ++nd) {
        bv[2 * nd]     = *(const bf16x8*)(vr0 + (size_t)(nd * 16) * T_);
        bv[2 * nd + 1] = *(const bf16x8*)(vr0 + (size_t)(nd * 16) * T_ + 32);
      }
    }
    // S^T = K * Q^T: col = q (lane&15), row = kv offset 4g+r within cj block
    f32x4 s[4] = {};
#pragma unroll
    for (int cj = 0; cj < 4; ++cj) {
      s[cj] = __builtin_amdgcn_mfma_f32_16x16x32_bf16(bk[2 * cj], bq0, s[cj], 0, 0, 0);
      s[cj] = __builtin_amdgcn_mfma_f32_16x16x32_bf16(bk[2 * cj + 1], bq1, s[cj], 0, 0, 0);
    }
    // prefetch next K tile into the just-consumed regs (hides L2 latency)
    if (kt < kt_hi) {
      const short* krn = kbase + (size_t)((kt + 1) * 64 + c) * D_ + g * 8;
#pragma unroll
      for (int cj = 0; cj < 4; ++cj) {
        bk[2 * cj]     = *(const bf16x8*)(krn + cj * 16 * D_);
        bk[2 * cj + 1] = *(const bf16x8*)(krn + cj * 16 * D_ + 32);
      }
    }
    // in-register softmax (scalar m/l per lane; row = q = c)
    const bool edge = (kt >= kt_hi) || (kt <= kt_lo + 1);
    float tmax = -3.0e38f;
#pragma unroll
    for (int cj = 0; cj < 4; ++cj)
#pragma unroll
      for (int r = 0; r < 4; ++r) {
        float v = s[cj][r] * SC2;
        if (edge) {
          int kv = kc0 + cj * 16 + 4 * g + r;
          v = (kv <= qgl && kv > qgl - wsz) ? v : -30000.0f;
        }
        s[cj][r] = v;
        tmax = fmaxf(tmax, v);
      }
    tmax = fmaxf(tmax, __shfl_xor(tmax, 16));
    tmax = fmaxf(tmax, __shfl_xor(tmax, 32));
    const float nm = fmaxf(m, tmax);
    const float fr = exp2fast(m - nm);
    m = nm;
    float psum = 0.0f;
    unsigned pb[8];
#pragma unroll
    for (int cj = 0; cj < 4; ++cj) {
      float p0 = exp2fast(s[cj][0] - nm), p1 = exp2fast(s[cj][1] - nm);
      float p2 = exp2fast(s[cj][2] - nm), p3 = exp2fast(s[cj][3] - nm);
      psum += (p0 + p1) + (p2 + p3);
      pb[2 * cj]     = pack2bf(p0, p1);
      pb[2 * cj + 1] = pack2bf(p2, p3);
    }
    psum += __shfl_xor(psum, 16);
    psum += __shfl_xor(psum, 32);
    l = l * fr + psum;
#pragma unroll
    for (int nd = 0; nd < 4; ++nd)
#pragma unroll
      for (int r = 0; r < 4; ++r) o[nd][r] *= fr;
    // P^T regs -> LDS (packed b64 writes), re-read as B-operand frags
#pragma unroll
    for (int cj = 0; cj < 4; ++cj) {
      unsigned long long w = ((unsigned long long)pb[2 * cj + 1] << 32) | pb[2 * cj];
      *(unsigned long long*)&spt[c][cj * 16 + 4 * g] = w;
    }
    asm volatile("s_waitcnt lgkmcnt(0)" ::: "memory");
#pragma unroll
    for (int ks = 0; ks < 2; ++ks) {
      bf16x8 bp = *(const bf16x8*)&spt[c][ks * 32 + g * 8];
#pragma unroll
      for (int nd = 0; nd < 4; ++nd)
        o[nd] = __builtin_amdgcn_mfma_f32_16x16x32_bf16(bv[2 * nd + ks], bp, o[nd], 0, 0, 0);
    }
  }
  // O^T: col = q = c (scalar l), row = d offset 4g+r within nd block
  const float inv = 1.0f / l;
#pragma unroll
  for (int nd = 0; nd < 4; ++nd) {
    unsigned d0 = pack2bf(o[nd][0] * inv, o[nd][1] * inv);
    unsigned d1 = pack2bf(o[nd][2] * inv, o[nd][3] * inv);
    unsigned long long w = ((unsigned long long)d1 << 32) | d0;
    *(unsigned long long*)(yb + ((size_t)b * T_ + t0 + c) * C_ + h * D_ + nd * 16 + 4 * g) = w;
  }
}

extern "C" void kernel_launch(void* const* d_in, const int* in_sizes, int n_in,
                              void* d_out, int out_size, void* d_ws, size_t ws_size,
                              hipStream_t stream) {
  const float* x    = (const float*)d_in[0];
  const float* ve   = (const float*)d_in[1];
  const float* cosp = (const float*)d_in[2];
  const float* sinp = (const float*)d_in[3];
  const float* Wq   = (const float*)d_in[4];
  const float* Wk   = (const float*)d_in[5];
  const float* Wv   = (const float*)d_in[6];
  const float* Wo   = (const float*)d_in[7];
  const float* Wg   = (const float*)d_in[8];
  const int*   winp = (const int*)d_in[9];
  float* out = (float*)d_out;
  char* ws = (char*)d_ws;

  const size_t MB = 1024 * 1024;
  short* xb   = (short*)(ws);              // 8 MiB : x bf16 (4096x1024)
  short* wT   = (short*)(ws + 8  * MB);    // 3 MiB : [Wq|Wk|Wv]^T bf16 (1536x1024)
  short* woT  = (short*)(ws + 11 * MB);    // 2 MiB : Wo^T bf16 (1024x1024)
  float* qkv  = (float*)(ws + 13 * MB);    // 24 MiB: qkv f32 (4096x1536)
  short* qb   = (short*)(ws + 37 * MB);    // 8 MiB : q bf16 (B,H,T,D)
  short* kbuf = (short*)(ws + 45 * MB);    // 2 MiB : k bf16 (B,KV,T,D)
  short* vT   = (short*)(ws + 47 * MB);    // 2 MiB : v bf16 (B,KV,D,T)
  short* yb   = (short*)(ws + 49 * MB);    // 8 MiB : attn out bf16 (B,T,C)

  k_cast<<<4096, 256, 0, stream>>>(x, xb, M_ * C_);
  k_transpose_all<<<dim3(80, 32), dim3(32, 8), 0, stream>>>(Wq, Wk, Wv, Wo, wT, woT);

  k_gemm<<<dim3(12, 32), 256, 0, stream>>>(xb, wT, qkv, M_, 1536, 1024);
  k_post<<<4096, 256, 0, stream>>>(qkv, x, ve, cosp, sinp, Wg, qb, kbuf, vT);
  k_attn<<<dim3(32, 32), 256, 0, stream>>>(qb, kbuf, vT, yb, winp);
  k_gemm<<<dim3(8, 32), 256, 0, stream>>>(yb, woT, out, M_, 1024, 1024);
}

// Round 5
// 131.044 us; speedup vs baseline: 1.6740x; 1.6520x over previous
//
#include <hip/hip_runtime.h>
#include <hip/hip_bf16.h>

#define B_ 2
#define T_ 2048
#define C_ 1024
#define H_ 16
#define KV_ 4
#define D_ 64
#define M_ (B_*T_)   // 4096

typedef __attribute__((ext_vector_type(4))) float f32x4;
typedef __attribute__((ext_vector_type(8))) short bf16x8;

__device__ __forceinline__ float exp2fast(float x) {
  return __builtin_amdgcn_exp2f(x);   // v_exp_f32 (2^x)
}

__device__ __forceinline__ unsigned short f2bfu(float f) {
  unsigned u = __builtin_bit_cast(unsigned, f);
  u += 0x7FFFu + ((u >> 16) & 1u);   // round-to-nearest-even
  return (unsigned short)(u >> 16);
}

__device__ __forceinline__ short f2bf(float f) {
  return (short)f2bfu(f);
}

__device__ __forceinline__ unsigned pack2bf(float a, float b) {
  return (unsigned)f2bfu(a) | ((unsigned)f2bfu(b) << 16);
}

__device__ __forceinline__ void gld_lds16(const void* g, void* l) {
  __builtin_amdgcn_global_load_lds(
      (const __attribute__((address_space(1))) void*)g,
      (__attribute__((address_space(3))) void*)l, 16, 0, 0);
}

// ---------------- cast f32 -> bf16, 4 elems/thread ----------------
__global__ __launch_bounds__(256) void k_cast(const float* __restrict__ in,
                                              short* __restrict__ out, int n) {
  int i = (blockIdx.x * 256 + threadIdx.x) * 4;
  if (i + 3 < n) {
    float4 f = *(const float4*)(in + i);
    short4 s;
    s.x = f2bf(f.x); s.y = f2bf(f.y); s.z = f2bf(f.z); s.w = f2bf(f.w);
    *(short4*)(out + i) = s;
  }
}

// ---------------- fused transpose+cast of Wq|Wk|Wv and Wo ----------------
// grid (80, 32), block (32,8). out[c][r] = bf16(in[r][c]); R = 1024 for all.
__global__ __launch_bounds__(256) void k_transpose_all(const float* __restrict__ Wq,
                                                       const float* __restrict__ Wk,
                                                       const float* __restrict__ Wv,
                                                       const float* __restrict__ Wo,
                                                       short* __restrict__ wT,
                                                       short* __restrict__ woT) {
  __shared__ float tile[32][33];
  int bx = blockIdx.x;
  const float* in; short* out; int Ncol, cb;
  if (bx < 32)      { in = Wq; out = wT;                       Ncol = 1024; cb = bx; }
  else if (bx < 40) { in = Wk; out = wT + (size_t)1024 * 1024; Ncol = 256;  cb = bx - 32; }
  else if (bx < 48) { in = Wv; out = wT + (size_t)1280 * 1024; Ncol = 256;  cb = bx - 40; }
  else              { in = Wo; out = woT;                      Ncol = 1024; cb = bx - 48; }
  const int R = 1024;
  int c0 = cb * 32, r0 = blockIdx.y * 32;
  int tx = threadIdx.x, ty = threadIdx.y;
#pragma unroll
  for (int i = 0; i < 32; i += 8)
    tile[ty + i][tx] = in[(size_t)(r0 + ty + i) * Ncol + c0 + tx];
  __syncthreads();
#pragma unroll
  for (int i = 0; i < 32; i += 8)
    out[(size_t)(c0 + ty + i) * R + r0 + tx] = f2bf(tile[tx][ty + i]);
}

// ---------------- bf16 GEMM: C(MxN f32) = A(MxK) * Bt(NxK)^T ----------------
// 128x128 tile, BK=32, 4 waves (2x2 of 64x64), mfma_f32_16x16x32_bf16
__global__ __launch_bounds__(256) void k_gemm(const short* __restrict__ A,
                                              const short* __restrict__ Bt,
                                              float* __restrict__ C,
                                              int M, int N, int K) {
  __shared__ short sA[128 * 32];
  __shared__ short sB[128 * 32];
  const int tid = threadIdx.x;
  const int wid = tid >> 6, lane = tid & 63;
  const int g = lane >> 4, c = lane & 15;
  const int wm = wid >> 1, wn = wid & 1;
  const int m0 = blockIdx.y * 128, n0 = blockIdx.x * 128;
  const int srow = lane >> 2, scol = (lane & 3) * 8;

  const short* Ag = A + (size_t)(m0 + wid * 32 + srow) * K + scol;
  const short* Bg = Bt + (size_t)(n0 + wid * 32 + srow) * K + scol;
  short* sAd0 = &sA[(wid * 2) * 512];
  short* sAd1 = &sA[(wid * 2 + 1) * 512];
  short* sBd0 = &sB[(wid * 2) * 512];
  short* sBd1 = &sB[(wid * 2 + 1) * 512];

  f32x4 acc[4][4] = {};

  for (int k0 = 0; k0 < K; k0 += 32) {
    gld_lds16(Ag + k0, sAd0);
    gld_lds16(Ag + (size_t)16 * K + k0, sAd1);
    gld_lds16(Bg + k0, sBd0);
    gld_lds16(Bg + (size_t)16 * K + k0, sBd1);
    __syncthreads();
    bf16x8 af[4], bfr[4];
#pragma unroll
    for (int i = 0; i < 4; ++i)
      af[i] = *(const bf16x8*)&sA[(wm * 64 + i * 16 + c) * 32 + g * 8];
#pragma unroll
    for (int j = 0; j < 4; ++j)
      bfr[j] = *(const bf16x8*)&sB[(wn * 64 + j * 16 + c) * 32 + g * 8];
#pragma unroll
    for (int i = 0; i < 4; ++i)
#pragma unroll
      for (int j = 0; j < 4; ++j)
        acc[i][j] = __builtin_amdgcn_mfma_f32_16x16x32_bf16(af[i], bfr[j], acc[i][j], 0, 0, 0);
    __syncthreads();
  }
#pragma unroll
  for (int i = 0; i < 4; ++i)
#pragma unroll
    for (int j = 0; j < 4; ++j) {
      int row = m0 + wm * 64 + i * 16 + g * 4;
      int col = n0 + wn * 64 + j * 16 + c;
      float* cp = C + (size_t)row * N + col;
#pragma unroll
      for (int r = 0; r < 4; ++r) cp[(size_t)r * N] = acc[i][j][r];
    }
}

// ---------------- gate + ve, RoPE, RMS-norm; emit q/k/vT bf16 ----------------
__global__ __launch_bounds__(256) void k_post(const float* __restrict__ qkv,
                                              const float* __restrict__ x,
                                              const float* __restrict__ ve,
                                              const float* __restrict__ cosp,
                                              const float* __restrict__ sinp,
                                              const float* __restrict__ Wg,
                                              short* __restrict__ qb,
                                              short* __restrict__ kb,
                                              short* __restrict__ vT) {
  const int row = blockIdx.x;            // b*T + t
  const int b = row >> 11, t = row & (T_ - 1);
  const int wid = threadIdx.x >> 6, lane = threadIdx.x & 63;
  const float* qrow = qkv + (size_t)row * 1536;
  const float cv = cosp[t * 32 + (lane & 31)];
  const float sv = sinp[t * 32 + (lane & 31)];

  for (int vi = wid; vi < 24; vi += 4) {
    if (vi < 20) {
      float val = (vi < 16) ? qrow[vi * 64 + lane] : qrow[1024 + (vi - 16) * 64 + lane];
      float other = __shfl_xor(val, 32);
      float r = (lane < 32) ? fmaf(val, cv, other * sv) : fmaf(val, cv, -other * sv);
      float ss = r * r;
      ss += __shfl_xor(ss, 1);  ss += __shfl_xor(ss, 2);  ss += __shfl_xor(ss, 4);
      ss += __shfl_xor(ss, 8);  ss += __shfl_xor(ss, 16); ss += __shfl_xor(ss, 32);
      float outv = r * rsqrtf(ss * (1.0f / 64.0f) + 1.1920929e-07f);
      if (vi < 16)
        qb[((size_t)(b * H_ + vi) * T_ + t) * D_ + lane] = f2bf(outv);
      else
        kb[((size_t)(b * KV_ + (vi - 16)) * T_ + t) * D_ + lane] = f2bf(outv);
    } else {
      int kvh = vi - 20;
      float val = qrow[1280 + kvh * 64 + lane];
      float xg = (lane < 32) ? x[(size_t)row * C_ + lane] * Wg[lane * KV_ + kvh] : 0.0f;
      xg += __shfl_xor(xg, 1);  xg += __shfl_xor(xg, 2);  xg += __shfl_xor(xg, 4);
      xg += __shfl_xor(xg, 8);  xg += __shfl_xor(xg, 16); xg += __shfl_xor(xg, 32);
      float gate = 2.0f / (1.0f + __expf(-xg));
      float vvv = fmaf(gate, ve[(size_t)row * (KV_ * D_) + kvh * 64 + lane], val);
      vT[((size_t)(b * KV_ + kvh) * D_ + lane) * T_ + t] = f2bf(vvv);
    }
  }
}

// ---------------- flash attention: block-cooperative LDS-staged K/V ----------------
// Block = 4 waves = 64 q rows of one (b,h). K double-buffered, V single-buffered
// in LDS, staged once per block via global_load_lds (coalesced). XOR chunk
// swizzle (chunk ^= row&7) applied at BOTH stage-source and ds_read.
__global__ __launch_bounds__(256, 4) void k_attn(const short* __restrict__ qg,
                                                 const short* __restrict__ kg,
                                                 const short* __restrict__ vg,
                                                 short* __restrict__ yb,
                                                 const int* __restrict__ winp) {
  const int wsz = *winp;
  const int qt = blockIdx.x, bh = blockIdx.y;
  const int b = bh >> 4, h = bh & 15;
  const int kvh = h >> 2;
  const int tid = threadIdx.x;
  const int wid = tid >> 6, lane = tid & 63;
  const int g = lane >> 4, c = lane & 15;
  const int t0 = qt * 64 + wid * 16;

  __shared__ short sK[2][64 * 64];
  __shared__ short sV[64 * 64];
  __shared__ short spt_all[4][16][72];
  short (*spt)[72] = spt_all[wid];

  const short* qbase = qg + ((size_t)(b * H_ + h) * T_ + t0) * D_;
  const bf16x8 bq0 = *(const bf16x8*)(qbase + c * D_ + g * 8);
  const bf16x8 bq1 = *(const bf16x8*)(qbase + c * D_ + 32 + g * 8);
  const short* kbase = kg + (size_t)(b * KV_ + kvh) * T_ * D_;
  const short* vbase = vg + (size_t)(b * KV_ + kvh) * D_ * T_;

  // staging geometry: issue i in {0,1}; row r = i*32 + wid*8 + (lane>>3);
  // source chunk pre-swizzled so linear LDS == swizzled layout.
  const int srow0 = wid * 8 + (lane >> 3);
  const int sq    = ((lane & 7) ^ ((lane >> 3) & 7)) * 8;   // element offset in row
  const int ldst0 = wid * 512;                               // shorts (wave-uniform)

  float m = -20000.0f, l = 0.0f;
  f32x4 o[4] = {};

  int lo = t0 - wsz + 1; if (lo < 0) lo = 0;
  const int kt_lo_w = lo >> 6;                 // wave's own first tile
  int lou = qt * 64 - wsz + 1; if (lou < 0) lou = 0;
  const int kt_lo_u = lou >> 6;                // block-union first tile
  const int kt_hi = qt;                        // uniform last tile
  const int qgl = t0 + c;
  const float SC2 = 0.125f * 1.44269504088896340736f;   // scale * log2(e)

  // prologue: stage K tile kt_lo_u into buf 0
  {
    const short* src = kbase + (size_t)(kt_lo_u * 64 + srow0) * D_ + sq;
    gld_lds16(src,                    &sK[0][ldst0]);
    gld_lds16(src + (size_t)32 * D_,  &sK[0][ldst0 + 2048]);
  }
  __syncthreads();

  int cb = 0;
  for (int kt = kt_lo_u; kt <= kt_hi; ++kt) {
    const int kc0 = kt * 64;
    // stage V(kt) and K(kt+1)
    {
      const short* vsrc = vbase + (size_t)srow0 * T_ + kc0 + sq;
      gld_lds16(vsrc,                   &sV[ldst0]);
      gld_lds16(vsrc + (size_t)32 * T_, &sV[ldst0 + 2048]);
    }
    if (kt < kt_hi) {
      const short* ksrc = kbase + (size_t)((kt + 1) * 64 + srow0) * D_ + sq;
      gld_lds16(ksrc,                   &sK[cb ^ 1][ldst0]);
      gld_lds16(ksrc + (size_t)32 * D_, &sK[cb ^ 1][ldst0 + 2048]);
    }
    // S^T = K * Q^T from sK[cb] (swizzled reads: 2-way banks, free)
    f32x4 s[4] = {};
#pragma unroll
    for (int cj = 0; cj < 4; ++cj) {
      const int rbase = (cj * 16 + c) * 64;
      const int sw = (c & 7);
      bf16x8 k0 = *(const bf16x8*)&sK[cb][rbase + ((g ^ sw) * 8)];
      bf16x8 k1 = *(const bf16x8*)&sK[cb][rbase + (((4 + g) ^ sw) * 8)];
      s[cj] = __builtin_amdgcn_mfma_f32_16x16x32_bf16(k0, bq0, s[cj], 0, 0, 0);
      s[cj] = __builtin_amdgcn_mfma_f32_16x16x32_bf16(k1, bq1, s[cj], 0, 0, 0);
    }
    // in-register softmax (scalar m/l per lane; q-row = c)
    const bool edge = (kt >= kt_hi) || (kt <= kt_lo_w + 1);
    float tmax = -3.0e38f;
#pragma unroll
    for (int cj = 0; cj < 4; ++cj)
#pragma unroll
      for (int r = 0; r < 4; ++r) {
        float v = s[cj][r] * SC2;
        if (edge) {
          int kv = kc0 + cj * 16 + 4 * g + r;
          v = (kv <= qgl && kv > qgl - wsz) ? v : -30000.0f;
        }
        s[cj][r] = v;
        tmax = fmaxf(tmax, v);
      }
    tmax = fmaxf(tmax, __shfl_xor(tmax, 16));
    tmax = fmaxf(tmax, __shfl_xor(tmax, 32));
    const float nm = fmaxf(m, tmax);
    const float fr = exp2fast(m - nm);
    m = nm;
    float psum = 0.0f;
    unsigned pb[8];
#pragma unroll
    for (int cj = 0; cj < 4; ++cj) {
      float p0 = exp2fast(s[cj][0] - nm), p1 = exp2fast(s[cj][1] - nm);
      float p2 = exp2fast(s[cj][2] - nm), p3 = exp2fast(s[cj][3] - nm);
      psum += (p0 + p1) + (p2 + p3);
      pb[2 * cj]     = pack2bf(p0, p1);
      pb[2 * cj + 1] = pack2bf(p2, p3);
    }
    psum += __shfl_xor(psum, 16);
    psum += __shfl_xor(psum, 32);
    l = l * fr + psum;
#pragma unroll
    for (int nd = 0; nd < 4; ++nd)
#pragma unroll
      for (int r = 0; r < 4; ++r) o[nd][r] *= fr;

    __syncthreads();   // drains vmcnt: sV (and next sK) ready; all waves synced

    // P^T regs -> per-wave LDS (packed b64), re-read as B-operand frags
#pragma unroll
    for (int cj = 0; cj < 4; ++cj) {
      unsigned long long w = ((unsigned long long)pb[2 * cj + 1] << 32) | pb[2 * cj];
      *(unsigned long long*)&spt[c][cj * 16 + 4 * g] = w;
    }
    asm volatile("s_waitcnt lgkmcnt(0)" ::: "memory");
#pragma unroll
    for (int ks = 0; ks < 2; ++ks) {
      bf16x8 bp = *(const bf16x8*)&spt[c][ks * 32 + g * 8];
#pragma unroll
      for (int nd = 0; nd < 4; ++nd) {
        const int rbase = (nd * 16 + c) * 64;
        bf16x8 bv = *(const bf16x8*)&sV[rbase + (((ks * 4 + g) ^ (c & 7)) * 8)];
        o[nd] = __builtin_amdgcn_mfma_f32_16x16x32_bf16(bv, bp, o[nd], 0, 0, 0);
      }
    }
    __syncthreads();   // protect sV / sK[cb] before next iteration's staging
    cb ^= 1;
  }
  // O^T: col = q = c (scalar l), row = d offset 4g+r within nd block
  const float inv = 1.0f / l;
#pragma unroll
  for (int nd = 0; nd < 4; ++nd) {
    unsigned d0 = pack2bf(o[nd][0] * inv, o[nd][1] * inv);
    unsigned d1 = pack2bf(o[nd][2] * inv, o[nd][3] * inv);
    unsigned long long w = ((unsigned long long)d1 << 32) | d0;
    *(unsigned long long*)(yb + ((size_t)b * T_ + t0 + c) * C_ + h * D_ + nd * 16 + 4 * g) = w;
  }
}

extern "C" void kernel_launch(void* const* d_in, const int* in_sizes, int n_in,
                              void* d_out, int out_size, void* d_ws, size_t ws_size,
                              hipStream_t stream) {
  const float* x    = (const float*)d_in[0];
  const float* ve   = (const float*)d_in[1];
  const float* cosp = (const float*)d_in[2];
  const float* sinp = (const float*)d_in[3];
  const float* Wq   = (const float*)d_in[4];
  const float* Wk   = (const float*)d_in[5];
  const float* Wv   = (const float*)d_in[6];
  const float* Wo   = (const float*)d_in[7];
  const float* Wg   = (const float*)d_in[8];
  const int*   winp = (const int*)d_in[9];
  float* out = (float*)d_out;
  char* ws = (char*)d_ws;

  const size_t MB = 1024 * 1024;
  short* xb   = (short*)(ws);              // 8 MiB : x bf16 (4096x1024)
  short* wT   = (short*)(ws + 8  * MB);    // 3 MiB : [Wq|Wk|Wv]^T bf16 (1536x1024)
  short* woT  = (short*)(ws + 11 * MB);    // 2 MiB : Wo^T bf16 (1024x1024)
  float* qkv  = (float*)(ws + 13 * MB);    // 24 MiB: qkv f32 (4096x1536)
  short* qb   = (short*)(ws + 37 * MB);    // 8 MiB : q bf16 (B,H,T,D)
  short* kbuf = (short*)(ws + 45 * MB);    // 2 MiB : k bf16 (B,KV,T,D)
  short* vT   = (short*)(ws + 47 * MB);    // 2 MiB : v bf16 (B,KV,D,T)
  short* yb   = (short*)(ws + 49 * MB);    // 8 MiB : attn out bf16 (B,T,C)

  k_cast<<<4096, 256, 0, stream>>>(x, xb, M_ * C_);
  k_transpose_all<<<dim3(80, 32), dim3(32, 8), 0, stream>>>(Wq, Wk, Wv, Wo, wT, woT);

  k_gemm<<<dim3(12, 32), 256, 0, stream>>>(xb, wT, qkv, M_, 1536, 1024);
  k_post<<<4096, 256, 0, stream>>>(qkv, x, ve, cosp, sinp, Wg, qb, kbuf, vT);
  k_attn<<<dim3(32, 32), 256, 0, stream>>>(qb, kbuf, vT, yb, winp);
  k_gemm<<<dim3(8, 32), 256, 0, stream>>>(yb, woT, out, M_, 1024, 1024);
}